// Round 12
// baseline (1275.741 us; speedup 1.0000x reference)
//
#include <hip/hip_runtime.h>

#define HW 65536
#define SIDE 256

typedef __attribute__((ext_vector_type(8))) short short8v;
typedef __attribute__((ext_vector_type(4))) float f32x4;
typedef __attribute__((ext_vector_type(8))) ushort ushort8v;

__device__ __forceinline__ ushort f2bf(float f) {
  unsigned int u = __builtin_bit_cast(unsigned int, f);
  u = (u + 0x7fff + ((u >> 16) & 1)) >> 16;
  return (ushort)u;
}
__device__ __forceinline__ float bf2f(unsigned int u) {
  return __builtin_bit_cast(float, (u & 0xffffu) << 16);
}
__device__ __forceinline__ float bflo(unsigned int d) {
  return __builtin_bit_cast(float, d << 16);
}
__device__ __forceinline__ float bfhi(unsigned int d) {
  return __builtin_bit_cast(float, d & 0xffff0000u);
}
__device__ __forceinline__ void gld16(const void* g, void* l) {
  __builtin_amdgcn_global_load_lds(
      (const __attribute__((address_space(1))) void*)g,
      (__attribute__((address_space(3))) void*)l, 16, 0, 0);
}

// ---------------------------------------------------------------------------
// Unified weight prep: all bf16 casts + bias concats + combined conv kernel.
__global__ __launch_bounds__(256) void k_prep(
    const float* __restrict__ W1, const float* __restrict__ Wv,
    const float* __restrict__ Wv1, const float* __restrict__ Wq,
    const float* __restrict__ Wk, const float* __restrict__ Wq1,
    const float* __restrict__ Wk1, const float* __restrict__ bq,
    const float* __restrict__ bk, const float* __restrict__ bq1,
    const float* __restrict__ bk1, const float* __restrict__ w7,
    const float* __restrict__ b7, const float* __restrict__ w5,
    const float* __restrict__ b5, const float* __restrict__ w3,
    const float* __restrict__ b3,
    ushort* __restrict__ W1b, ushort* __restrict__ Wvb,
    ushort* __restrict__ Wv1b, ushort* __restrict__ Wqkb,
    ushort* __restrict__ Wqk1b, float* __restrict__ bqk,
    float* __restrict__ bqk1, float* __restrict__ wc, float* __restrict__ bc) {
  const int i = blockIdx.x * 256 + threadIdx.x;
  if (i < 524288) { W1b[i] = f2bf(W1[i]); return; }
  if (i < 786432) { int j = i - 524288; Wvb[j] = f2bf(Wv[j]); return; }
  if (i < 1048576) { int j = i - 786432; Wv1b[j] = f2bf(Wv1[j]); return; }
  if (i < 1081344) { int j = i - 1048576; Wqkb[j] = f2bf(Wq[j]); return; }
  if (i < 1114112) { int j = i - 1081344; Wqkb[32768 + j] = f2bf(Wk[j]); return; }
  if (i < 1146880) { int j = i - 1114112; Wqk1b[j] = f2bf(Wq1[j]); return; }
  if (i < 1179648) { int j = i - 1146880; Wqk1b[32768 + j] = f2bf(Wk1[j]); return; }
  if (i < 1179904) {
    int j = i - 1179648;
    if (j < 64) bqk[j] = bq[j];
    else if (j < 128) bqk[j] = bk[j - 64];
    else if (j < 192) bqk1[j - 128] = bq1[j - 128];
    else bqk1[j - 128] = bk1[j - 192];
    return;
  }
  if (i < 1180928) {
    const int c = i - 1179904;
    float w[49];
#pragma unroll
    for (int t = 0; t < 49; t++) w[t] = w7[c * 49 + t];
    for (int dy = 0; dy < 5; dy++)
      for (int dx = 0; dx < 5; dx++)
        w[(dy + 1) * 7 + (dx + 1)] += w5[c * 25 + dy * 5 + dx];
    for (int dy = 0; dy < 3; dy++)
      for (int dx = 0; dx < 3; dx++)
        w[(dy + 2) * 7 + (dx + 2)] += w3[c * 9 + dy * 3 + dx];
    w[3 * 7 + 3] += 1.0f;
#pragma unroll
    for (int t = 0; t < 49; t++) wc[c * 49 + t] = w[t];
    bc[c] = b7[c] + b5[c] + b3[c];
  }
}

// ---------------------------------------------------------------------------
// Vectorized transpose h0 [N][1024] fp32 -> X [1024][N] bf16.
__global__ __launch_bounds__(256) void k_transpose_nc_v(
    const float* __restrict__ in, ushort* __restrict__ out) {
  __shared__ ushort t[64][64];
  const int c0 = blockIdx.x << 6, r0 = blockIdx.y << 6;
  const int tid = threadIdx.x;
#pragma unroll
  for (int p = 0; p < 2; p++) {
    const int r = (tid >> 3) + p * 32, c8 = tid & 7;
    const float4 f0 = *(const float4*)&in[(size_t)(r0 + r) * 1024 + c0 + c8 * 8];
    const float4 f1 = *(const float4*)&in[(size_t)(r0 + r) * 1024 + c0 + c8 * 8 + 4];
    ushort8v v;
    v[0] = f2bf(f0.x); v[1] = f2bf(f0.y); v[2] = f2bf(f0.z); v[3] = f2bf(f0.w);
    v[4] = f2bf(f1.x); v[5] = f2bf(f1.y); v[6] = f2bf(f1.z); v[7] = f2bf(f1.w);
    *(ushort8v*)&t[r][(c8 ^ ((r >> 3) & 7)) * 8] = v;
  }
  __syncthreads();
#pragma unroll
  for (int p = 0; p < 2; p++) {
    const int c = (tid >> 3) + p * 32, r8 = tid & 7;
    ushort8v v;
#pragma unroll
    for (int j = 0; j < 8; j++) {
      const int rr = r8 * 8 + j;
      v[j] = t[rr][(((c >> 3) ^ r8) << 3) + (c & 7)];
    }
    *(ushort8v*)&out[(size_t)(c0 + c) * HW + r0 + r8 * 8] = v;
  }
}

// ---------------------------------------------------------------------------
// Generic batched bf16 transpose (vectorized): in [R][C] -> out [C][R].
__global__ __launch_bounds__(256) void k_trv(const ushort* __restrict__ in,
    ushort* __restrict__ out, int R, int C, long long bs) {
  __shared__ ushort t[64][64];
  const size_t base = (size_t)blockIdx.z * bs;
  const int c0 = blockIdx.x << 6, r0 = blockIdx.y << 6;
  const int tid = threadIdx.x;
#pragma unroll
  for (int p = 0; p < 2; p++) {
    const int r = (tid >> 3) + p * 32, c8 = tid & 7;
    const ushort8v v = *(const ushort8v*)&in[base + (size_t)(r0 + r) * C + c0 + c8 * 8];
    *(ushort8v*)&t[r][(c8 ^ ((r >> 3) & 7)) * 8] = v;
  }
  __syncthreads();
#pragma unroll
  for (int p = 0; p < 2; p++) {
    const int c = (tid >> 3) + p * 32, r8 = tid & 7;
    ushort8v v;
#pragma unroll
    for (int j = 0; j < 8; j++) {
      const int rr = r8 * 8 + j;
      v[j] = t[rr][(((c >> 3) ^ r8) << 3) + (c & 7)];
    }
    *(ushort8v*)&out[base + (size_t)(c0 + c) * R + r0 + r8 * 8] = v;
  }
}

// ---------------------------------------------------------------------------
// Depthwise 7x7 conv, CHW, bf16 LDS tile. grid (8 stripes, 1024 ch).
__global__ __launch_bounds__(256) void k_dwconv7(const ushort* __restrict__ X,
    const float* __restrict__ wc, const float* __restrict__ bc,
    ushort* __restrict__ out) {
  __shared__ ushort tile[38][272];
  const int c = blockIdx.y;
  const int y0 = blockIdx.x << 5;
  const int tid = threadIdx.x;
  const ushort* Xc = X + (size_t)c * HW;

  float w[49];
#pragma unroll
  for (int i = 0; i < 49; i++) w[i] = wc[c * 49 + i];
  const float bcv = bc[c];

  if (tid < 76) {
    const int r = tid >> 1;
    ushort8v z = {0, 0, 0, 0, 0, 0, 0, 0};
    *(ushort8v*)&tile[r][(tid & 1) ? 264 : 0] = z;
  }
  for (int i = tid; i < 38 * 32; i += 256) {
    const int r = i >> 5, j8 = i & 31;
    const int y = y0 - 3 + r;
    ushort8v v = {0, 0, 0, 0, 0, 0, 0, 0};
    if (y >= 0 && y < SIDE) v = *(const ushort8v*)&Xc[y * SIDE + j8 * 8];
    *(ushort8v*)&tile[r][8 + j8 * 8] = v;
  }
  __syncthreads();

  const int t0 = tid & 63;
  const int ry = (tid >> 6) << 3;
  float acc[8][4] = {};
#pragma unroll
  for (int r = 0; r < 14; r++) {
    const uint2 ua = *(const uint2*)&tile[ry + r][(t0 << 2) + 4];
    const uint2 ub = *(const uint2*)&tile[ry + r][(t0 << 2) + 8];
    const uint2 uc = *(const uint2*)&tile[ry + r][(t0 << 2) + 12];
    float rv[12];
    rv[0] = bflo(ua.x); rv[1] = bfhi(ua.x); rv[2] = bflo(ua.y); rv[3] = bfhi(ua.y);
    rv[4] = bflo(ub.x); rv[5] = bfhi(ub.x); rv[6] = bflo(ub.y); rv[7] = bfhi(ub.y);
    rv[8] = bflo(uc.x); rv[9] = bfhi(uc.x); rv[10] = bflo(uc.y); rv[11] = bfhi(uc.y);
#pragma unroll
    for (int m = 0; m < 8; m++) {
      const int dy = r - m;
      if (dy < 0 || dy > 6) continue;
#pragma unroll
      for (int dx = 0; dx < 7; dx++) {
        const float ww = w[dy * 7 + dx];
#pragma unroll
        for (int o = 0; o < 4; o++) acc[m][o] += ww * rv[o + 1 + dx];
      }
    }
  }
#pragma unroll
  for (int m = 0; m < 8; m++) {
    ushort4 o4 = {f2bf(acc[m][0] + bcv), f2bf(acc[m][1] + bcv),
                  f2bf(acc[m][2] + bcv), f2bf(acc[m][3] + bcv)};
    *(ushort4*)&out[(size_t)c * HW + (y0 + ry + m) * SIDE + (t0 << 2)] = o4;
  }
}

// ---------------------------------------------------------------------------
// 256x128 counted-vmcnt pipelined GEMM for M=512, N=65536 shapes (fc1 / v).
template <int K, int RELU, int TRN>
__global__ __launch_bounds__(512) void k_mm8(
    const ushort* __restrict__ A, int lda,
    const ushort* __restrict__ B, int ldb,
    const float* __restrict__ bias,
    ushort* __restrict__ Cb, int ldc,
    ushort* __restrict__ Ct, int ldt) {
  constexpr int NT = K / 32;
  __shared__ __align__(16) ushort SM[2 * 12288];
  const int tid = threadIdx.x;
  const int lane = tid & 63, wv = tid >> 6;

  const int id = blockIdx.x;
  const int wg = (id & 7) * 128 + (id >> 3);
  const int bm = (wg >> 9) << 8;
  const int bn = (wg & 511) << 7;

  const int l4 = lane >> 2;
  const int sch = (lane & 3) ^ (l4 & 3);
  const int rA0 = (wv * 2) * 16 + l4;
  const int rA1 = (wv * 2 + 1) * 16 + l4;
  const int rB = wv * 16 + l4;
  const ushort* ApS0 = A + (size_t)(bm + rA0) * lda + sch * 8;
  const ushort* ApS1 = A + (size_t)(bm + rA1) * lda + sch * 8;
  const ushort* BpS = B + (size_t)(bn + rB) * ldb + sch * 8;
  const int dA0 = (wv * 2) * 512 + lane * 8;
  const int dA1 = (wv * 2 + 1) * 512 + lane * 8;
  const int dB = wv * 512 + lane * 8;

  const int wm = wv & 3, wn = wv >> 2;
  const int fr = lane & 15, kq = lane >> 4;
  int offA[4], offB[4];
#pragma unroll
  for (int mi = 0; mi < 4; mi++) {
    const int row = wm * 64 + mi * 16 + fr;
    offA[mi] = row * 32 + ((kq ^ (row & 3)) << 3);
  }
#pragma unroll
  for (int ni = 0; ni < 4; ni++) {
    const int row = wn * 64 + ni * 16 + fr;
    offB[ni] = 8192 + row * 32 + ((kq ^ (row & 3)) << 3);
  }

  f32x4 acc[4][4];
#pragma unroll
  for (int mi = 0; mi < 4; mi++)
#pragma unroll
    for (int ni = 0; ni < 4; ni++) acc[mi][ni] = (f32x4){0.f, 0.f, 0.f, 0.f};

#define STAGE8(bufbase, k0)                         \
  do {                                              \
    gld16(ApS0 + (k0), &SM[(bufbase) + dA0]);       \
    gld16(ApS1 + (k0), &SM[(bufbase) + dA1]);       \
    gld16(BpS + (k0), &SM[(bufbase) + 8192 + dB]);  \
  } while (0)

  STAGE8(0, 0);
  STAGE8(12288, 32);
  asm volatile("s_waitcnt vmcnt(3)" ::: "memory");
  __builtin_amdgcn_s_barrier();

  int cur = 0;
#pragma unroll 2
  for (int t = 0; t < NT; ++t) {
    const int base = cur ? 12288 : 0;
    short8v a[4], b2[4];
#pragma unroll
    for (int mi = 0; mi < 4; mi++) a[mi] = *(const short8v*)&SM[base + offA[mi]];
#pragma unroll
    for (int ni = 0; ni < 4; ni++) b2[ni] = *(const short8v*)&SM[base + offB[ni]];
    asm volatile("s_waitcnt lgkmcnt(0)" ::: "memory");
    __builtin_amdgcn_s_barrier();
    const int ts = (t + 2 < NT) ? (t + 2) : (NT - 1);
    STAGE8(base, ts << 5);
    __builtin_amdgcn_s_setprio(1);
#pragma unroll
    for (int mi = 0; mi < 4; mi++)
#pragma unroll
      for (int ni = 0; ni < 4; ni++)
        acc[mi][ni] = __builtin_amdgcn_mfma_f32_16x16x32_bf16(b2[ni], a[mi], acc[mi][ni], 0, 0, 0);
    __builtin_amdgcn_s_setprio(0);
    asm volatile("s_waitcnt vmcnt(3)" ::: "memory");
    __builtin_amdgcn_s_barrier();
    cur ^= 1;
  }
#undef STAGE8
  asm volatile("s_waitcnt vmcnt(0)" ::: "memory");
  __builtin_amdgcn_s_barrier();

  ushort tb[4][4][4];
#pragma unroll
  for (int mi = 0; mi < 4; mi++) {
    const int row = bm + wm * 64 + mi * 16 + fr;
    const float bs1 = bias[row];
#pragma unroll
    for (int ni = 0; ni < 4; ni++) {
      const int col = bn + wn * 64 + ni * 16 + (kq << 2);
      float4 v;
      v.x = acc[mi][ni][0] + bs1; v.y = acc[mi][ni][1] + bs1;
      v.z = acc[mi][ni][2] + bs1; v.w = acc[mi][ni][3] + bs1;
      if (RELU) {
        v.x = fmaxf(v.x, 0.f); v.y = fmaxf(v.y, 0.f);
        v.z = fmaxf(v.z, 0.f); v.w = fmaxf(v.w, 0.f);
      }
      const ushort4 u = {f2bf(v.x), f2bf(v.y), f2bf(v.z), f2bf(v.w)};
      *(ushort4*)&Cb[(size_t)row * ldc + col] = u;
      if (TRN) {
        tb[mi][ni][0] = u.x; tb[mi][ni][1] = u.y;
        tb[mi][ni][2] = u.z; tb[mi][ni][3] = u.w;
      }
    }
  }

  if constexpr (TRN) {
    ushort* St = SM;
#pragma unroll
    for (int hh = 0; hh < 2; hh++) {
      __builtin_amdgcn_s_barrier();
      if (wn == hh) {
#pragma unroll
        for (int mi = 0; mi < 4; mi++) {
          const int cl = wm * 64 + mi * 16 + fr;
#pragma unroll
          for (int ni = 0; ni < 4; ni++) {
            const int nl = ni * 16 + (kq << 2);
#pragma unroll
            for (int r = 0; r < 4; r++) St[(nl + r) * 256 + cl] = tb[mi][ni][r];
          }
        }
      }
      __builtin_amdgcn_s_barrier();
      const int cid = tid * 4;
      const int rowo = cid >> 5;
#pragma unroll
      for (int j = 0; j < 4; j++) {
        const int ch = (cid + j) & 31;
        const ushort8v vv = *(const ushort8v*)&St[rowo * 256 + ch * 8];
        *(ushort8v*)&Ct[(size_t)(bn + hh * 64 + rowo) * ldt + bm + ch * 8] = vv;
      }
    }
  }
}

// ---------------------------------------------------------------------------
// bf16 MFMA GEMM, 128xBN tile, BK=32, 4 waves, global_load_lds staging,
// swapped-operand MFMA (vectorized C stores).
// SWZ: 0 none; 2 grid (2,2,256) flat; 3 grid (4,2,256) flat;
//      4 DUAL-energy (2048 blocks: two (2,2,256) jobs);
//      5 DUAL-map (4096 blocks: two (4,2,256) jobs).
// For DUAL modes the second job's operands come from A2/B2/Cb2 (+strides).
template <int BN, int BIAS, int RELU, int OUTF, int OUTB, int SWZ>
__global__ __launch_bounds__(256) void k_mm(
    const ushort* A, int lda, long long bsA,
    const ushort* B, int ldb, long long bsB,
    const float* __restrict__ bias,
    float* __restrict__ Cf, ushort* Cb, int ldc, long long bsC,
    const ushort* A2, int lda2, long long bsA2,
    const ushort* B2, int ldb2, long long bsB2,
    ushort* Cb2, int K) {
  static_assert(BN == 64 || BN == 128, "BN");
  constexpr int FN = BN / 32;
  __shared__ __align__(16) ushort SMEM[128 * 32 + BN * 32];
  ushort* As = SMEM;
  ushort* Bs = SMEM + 128 * 32;
  const int tid = threadIdx.x;

  int bx, by, bz, sec = 0;
  if constexpr (SWZ == 0) {
    bx = blockIdx.x; by = blockIdx.y; bz = blockIdx.z;
  } else if constexpr (SWZ == 2) {   // logical (2,2,256)
    const int id = blockIdx.x, l = id >> 3;
    bz = (id & 7) * 32 + (l >> 2); bx = l & 1; by = (l >> 1) & 1;
  } else if constexpr (SWZ == 3) {   // logical (4,2,256)
    const int id = blockIdx.x, l = id >> 3;
    bz = (id & 7) * 32 + (l >> 3); bx = l & 3; by = (l >> 2) & 1;
  } else if constexpr (SWZ == 4) {   // dual (2,2,256) x2
    const int id = blockIdx.x, l = id >> 3;
    sec = l >> 7;
    const int l2 = l & 127;
    bz = (id & 7) * 32 + (l2 >> 2); bx = l2 & 1; by = (l2 >> 1) & 1;
  } else {                            // SWZ==5: dual (4,2,256) x2
    const int id = blockIdx.x, l = id >> 3;
    sec = l >> 8;
    const int l2 = l & 255;
    bz = (id & 7) * 32 + (l2 >> 3); bx = l2 & 3; by = (l2 >> 2) & 1;
  }
  if constexpr (SWZ >= 4) {
    if (sec) {
      A = A2; lda = lda2; bsA = bsA2;
      B = B2; ldb = ldb2; bsB = bsB2;
      Cb = Cb2;
    }
  }

  const int bm = bx << 7, bn = by * BN;
  const long long zA = (long long)bz * bsA;
  const long long zB = (long long)bz * bsB;
  const long long zC = (long long)bz * bsC;

  const int sr = tid >> 2, sq = tid & 3;
  const int sw0 = (sr >> 1) & 3;
  const int sw1 = ((sr + 64) >> 1) & 3;
  const ushort* Ap0 = A + zA + (size_t)(bm + sr) * lda + ((sq ^ sw0) << 3);
  const ushort* Ap1 = A + zA + (size_t)(bm + sr + 64) * lda + ((sq ^ sw1) << 3);
  const ushort* Bp0 = B + zB + (size_t)(bn + sr) * ldb + ((sq ^ sw0) << 3);
  const ushort* Bp1 = nullptr;
  if constexpr (BN == 128)
    Bp1 = B + zB + (size_t)(bn + sr + 64) * ldb + ((sq ^ sw1) << 3);
  ushort* wA0 = &As[sr * 32 + sq * 8];
  ushort* wA1 = &As[(sr + 64) * 32 + sq * 8];
  ushort* wB0 = &Bs[sr * 32 + sq * 8];
  ushort* wB1 = nullptr;
  if constexpr (BN == 128) wB1 = &Bs[(sr + 64) * 32 + sq * 8];

  const int lane = tid & 63, wv = tid >> 6;
  const int wm = wv & 1, wn = wv >> 1;
  const int fr = lane & 15, kq = lane >> 4;
  int offA[4], offB[FN];
#pragma unroll
  for (int mi = 0; mi < 4; mi++) {
    const int row = wm * 64 + mi * 16 + fr;
    offA[mi] = row * 32 + ((kq ^ ((row >> 1) & 3)) << 3);
  }
#pragma unroll
  for (int ni = 0; ni < FN; ni++) {
    const int row = wn * (BN / 2) + ni * 16 + fr;
    offB[ni] = row * 32 + ((kq ^ ((row >> 1) & 3)) << 3);
  }

  f32x4 acc[4][FN];
#pragma unroll
  for (int mi = 0; mi < 4; mi++)
#pragma unroll
    for (int ni = 0; ni < FN; ni++) acc[mi][ni] = (f32x4){0.f, 0.f, 0.f, 0.f};

  for (int k0 = 0; k0 < K; k0 += 32) {
    __syncthreads();
    gld16(Ap0 + k0, wA0);
    gld16(Ap1 + k0, wA1);
    gld16(Bp0 + k0, wB0);
    if constexpr (BN == 128) gld16(Bp1 + k0, wB1);
    __syncthreads();
    short8v a[4], b[FN];
#pragma unroll
    for (int mi = 0; mi < 4; mi++) a[mi] = *(const short8v*)&As[offA[mi]];
#pragma unroll
    for (int ni = 0; ni < FN; ni++) b[ni] = *(const short8v*)&Bs[offB[ni]];
#pragma unroll
    for (int mi = 0; mi < 4; mi++)
#pragma unroll
      for (int ni = 0; ni < FN; ni++)
        acc[mi][ni] = __builtin_amdgcn_mfma_f32_16x16x32_bf16(b[ni], a[mi], acc[mi][ni], 0, 0, 0);
  }

#pragma unroll
  for (int mi = 0; mi < 4; mi++) {
    const int row = bm + wm * 64 + mi * 16 + fr;
    const float bs1 = (BIAS == 1) ? bias[row] : 0.f;
#pragma unroll
    for (int ni = 0; ni < FN; ni++) {
      const int col = bn + wn * (BN / 2) + ni * 16 + (kq << 2);
      float4 v;
      v.x = acc[mi][ni][0]; v.y = acc[mi][ni][1];
      v.z = acc[mi][ni][2]; v.w = acc[mi][ni][3];
      if (BIAS == 1) { v.x += bs1; v.y += bs1; v.z += bs1; v.w += bs1; }
      if (BIAS == 2) {
        const float4 bc4 = *(const float4*)&bias[col];
        v.x += bc4.x; v.y += bc4.y; v.z += bc4.z; v.w += bc4.w;
      }
      if (RELU) {
        v.x = fmaxf(v.x, 0.f); v.y = fmaxf(v.y, 0.f);
        v.z = fmaxf(v.z, 0.f); v.w = fmaxf(v.w, 0.f);
      }
      const size_t idx = (size_t)(zC + (size_t)row * ldc + col);
      if (OUTF) *(float4*)&Cf[idx] = v;
      if (OUTB) {
        ushort4 u = {f2bf(v.x), f2bf(v.y), f2bf(v.z), f2bf(v.w)};
        *(ushort4*)&Cb[idx] = u;
      }
    }
  }
}

// ---------------------------------------------------------------------------
// Vectorized dual softmax (2 columns/thread, uint loads).
// Blocks 0..127: W path (cols = flat n, stride HW).
// Blocks 128..255: H path (cols = (w,g), base w*HW+g, stride 256).
__global__ __launch_bounds__(256) void k_softmax2v(const ushort* __restrict__ EW,
    ushort* __restrict__ AW, const ushort* __restrict__ EH,
    ushort* __restrict__ AH) {
  const int b = blockIdx.x, tid = threadIdx.x;
  const ushort* E;
  ushort* A;
  size_t base;
  int hs;
  if (b < 128) {
    E = EW; A = AW; hs = HW;
    base = (size_t)b * 512 + tid * 2;
  } else {
    E = EH; A = AH; hs = 256;
    const int w = (b - 128) * 2 + (tid >> 7);
    base = (size_t)w * HW + (tid & 127) * 2;
  }
  float m0 = -3.4e38f, m1 = -3.4e38f, s0 = 0.f, s1 = 0.f;
  for (int h = 0; h < 256; h++) {
    const unsigned int u = *(const unsigned int*)&E[base + (size_t)h * hs];
    const float x0 = bflo(u), x1 = bfhi(u);
    const float n0 = fmaxf(m0, x0), n1 = fmaxf(m1, x1);
    s0 = s0 * __expf(m0 - n0) + __expf(x0 - n0);
    s1 = s1 * __expf(m1 - n1) + __expf(x1 - n1);
    m0 = n0; m1 = n1;
  }
  const float i0 = 1.0f / s0, i1 = 1.0f / s1;
  for (int h = 0; h < 256; h++) {
    const size_t idx = base + (size_t)h * hs;
    const unsigned int u = *(const unsigned int*)&E[idx];
    const ushort r0 = f2bf(__expf(bflo(u) - m0) * i0);
    const ushort r1 = f2bf(__expf(bfhi(u) - m1) * i1);
    *(unsigned int*)&A[idx] = (unsigned int)r0 | ((unsigned int)r1 << 16);
  }
}

// ---------------------------------------------------------------------------
// Vectorized merge: outB[c][h][w] = f2bf(g*(O + TH^T) + CN). outB aliases CN.
__global__ __launch_bounds__(256) void k_merge3(const ushort* __restrict__ O,
    const ushort* __restrict__ TH, const ushort* __restrict__ CN,
    const float* __restrict__ gammap, ushort* __restrict__ outB) {
  __shared__ ushort t[64][64];
  const float g = *gammap;
  const size_t base = (size_t)blockIdx.z * HW;
  const int h0 = blockIdx.y << 6, w0 = blockIdx.x << 6;
  const int tid = threadIdx.x;
#pragma unroll
  for (int p = 0; p < 2; p++) {
    const int r = (tid >> 3) + p * 32, c8 = tid & 7;
    const ushort8v v = *(const ushort8v*)&TH[base + (w0 + r) * SIDE + h0 + c8 * 8];
    *(ushort8v*)&t[r][(c8 ^ ((r >> 3) & 7)) * 8] = v;
  }
  __syncthreads();
#pragma unroll
  for (int p = 0; p < 2; p++) {
    const int h = (tid >> 3) + p * 32, r8 = tid & 7;
    const size_t idx = base + (h0 + h) * SIDE + w0 + r8 * 8;
    const ushort8v o8 = *(const ushort8v*)&O[idx];
    const ushort8v c8v = *(const ushort8v*)&CN[idx];
    ushort8v res;
#pragma unroll
    for (int j = 0; j < 8; j++) {
      const int rr = r8 * 8 + j;
      const float th = bf2f(t[rr][(((h >> 3) ^ r8) << 3) + (h & 7)]);
      res[j] = f2bf(g * (bf2f(o8[j]) + th) + bf2f(c8v[j]));
    }
    *(ushort8v*)&outB[idx] = res;
  }
}

// ---------------------------------------------------------------------------
// logits, 2 n/thread, uint loads, float2 store.
__global__ __launch_bounds__(256) void k_logits2(const ushort* __restrict__ X,
    const float* __restrict__ Wfc, const float* __restrict__ bfc,
    float* __restrict__ L) {
  const int n0 = (blockIdx.x * 256 + threadIdx.x) * 2;
  float s0 = 0.f, s1 = 0.f;
  for (int j = 0; j < 512; j++) {
    const unsigned int u = *(const unsigned int*)&X[(size_t)j * HW + n0];
    const float wj = Wfc[j];
    s0 += bflo(u) * wj;
    s1 += bfhi(u) * wj;
  }
  float2 o = {s0 + bfc[0], s1 + bfc[0]};
  *(float2*)&L[n0] = o;
}

__global__ __launch_bounds__(256) void k_smax_reduce(const float* __restrict__ L,
                                                     float* __restrict__ red) {
  __shared__ float sm[256];
  const int tid = threadIdx.x;
  float m = -3.4e38f;
  for (int i = tid; i < HW; i += 256) m = fmaxf(m, L[i]);
  sm[tid] = m;
  __syncthreads();
  for (int s = 128; s > 0; s >>= 1) {
    if (tid < s) sm[tid] = fmaxf(sm[tid], sm[tid + s]);
    __syncthreads();
  }
  const float M = sm[0];
  __syncthreads();
  float sum = 0.f;
  for (int i = tid; i < HW; i += 256) sum += expf(L[i] - M);
  sm[tid] = sum;
  __syncthreads();
  for (int s = 128; s > 0; s >>= 1) {
    if (tid < s) sm[tid] += sm[tid + s];
    __syncthreads();
  }
  if (tid == 0) { red[0] = M; red[1] = sm[0]; }
}

__global__ __launch_bounds__(256) void k_smax_write(const float* __restrict__ L,
    const float* __restrict__ red, float* __restrict__ out) {
  const int n = blockIdx.x * 256 + threadIdx.x;
  out[n] = expf(L[n] - red[0]) * (1.0f / red[1]);
}

// ---------------------------------------------------------------------------
extern "C" void kernel_launch(void* const* d_in, const int* in_sizes, int n_in,
                              void* d_out, int out_size, void* d_ws, size_t ws_size,
                              hipStream_t stream) {
  const float* h0 = (const float*)d_in[0];
  const float* w7 = (const float*)d_in[1];
  const float* b7 = (const float*)d_in[2];
  const float* w5 = (const float*)d_in[3];
  const float* b5 = (const float*)d_in[4];
  const float* w3 = (const float*)d_in[5];
  const float* b3 = (const float*)d_in[6];
  const float* W1 = (const float*)d_in[7];
  const float* b1 = (const float*)d_in[8];
  const float* Wq = (const float*)d_in[9];
  const float* bq = (const float*)d_in[10];
  const float* Wk = (const float*)d_in[11];
  const float* bk = (const float*)d_in[12];
  const float* Wv = (const float*)d_in[13];
  const float* bv = (const float*)d_in[14];
  const float* gamma = (const float*)d_in[15];
  const float* Wq1 = (const float*)d_in[16];
  const float* bq1 = (const float*)d_in[17];
  const float* Wk1 = (const float*)d_in[18];
  const float* bk1 = (const float*)d_in[19];
  const float* Wv1 = (const float*)d_in[20];
  const float* bv1 = (const float*)d_in[21];
  const float* gamma1 = (const float*)d_in[22];
  const float* Wfc = (const float*)d_in[23];
  const float* bfc = (const float*)d_in[24];

  char* W = (char*)d_ws;
  const size_t MB = 1 << 20;
  ushort* Xb    = (ushort*)(W + 0);          // [0,128) bf16 CHW conv input
  ushort* H2b   = (ushort*)(W + 0);          // [0,64) bf16 h2/out1/out2 CHW
  ushort* H2t   = (ushort*)(W + 64 * MB);    // [64,128) bf16 act [n][512]
  ushort* qkt   = (ushort*)(W + 128 * MB);   // [128,144) bf16 [n][128]
  ushort* AttW  = (ushort*)(W + 144 * MB);   // [144,176)
  ushort* AttH  = (ushort*)(W + 176 * MB);   // [176,208)
  ushort* H1b   = (ushort*)(W + 256 * MB);   // [256,384) bf16 conv out CHW
  ushort* H1t   = (ushort*)(W + 384 * MB);   // [384,512) bf16 [n][1024]
  ushort* Vb    = (ushort*)(W + 384 * MB);   // [384,448) bf16 (after H1t dead)
  ushort* vTb   = (ushort*)(W + 448 * MB);   // [448,512) bf16
  ushort* Ob    = (ushort*)(W + 512 * MB);   // [512,576) bf16 map-W out
  ushort* THbb  = (ushort*)(W + 576 * MB);   // [576,640) bf16 map-H out
  ushort* EbW   = (ushort*)(W + 640 * MB);   // [640,672) bf16 energy W
  ushort* EbH   = (ushort*)(W + 672 * MB);   // [672,704) bf16 energy H
  ushort* W1b   = (ushort*)(W + 704 * MB);
  ushort* Wvb   = (ushort*)(W + 705 * MB);
  ushort* Wv1b  = (ushort*)(W + 705 * MB + 512 * 1024);
  ushort* Wqkb  = (ushort*)(W + 706 * MB);
  ushort* Wqk1b = (ushort*)(W + 706 * MB + 128 * 1024);
  float*  wcomb = (float*)(W + 706 * MB + 256 * 1024);
  float*  bcomb = (float*)(W + 706 * MB + 464 * 1024);
  float*  bqk   = (float*)(W + 706 * MB + 472 * 1024);
  float*  bqk1  = (float*)(W + 706 * MB + 474 * 1024);
  float*  L     = (float*)(W + 707 * MB);
  float*  red   = (float*)(W + 707 * MB + 256 * 1024);

  // --- unified weight prep (1 launch) ---
  k_prep<<<4613, 256, 0, stream>>>(W1, Wv, Wv1, Wq, Wk, Wq1, Wk1,
                                   bq, bk, bq1, bk1, w7, b7, w5, b5, w3, b3,
                                   W1b, Wvb, Wv1b, Wqkb, Wqk1b, bqk, bqk1,
                                   wcomb, bcomb);

  // --- PPEG ---
  k_transpose_nc_v<<<dim3(16, 1024), 256, 0, stream>>>(h0, Xb);
  k_dwconv7<<<dim3(8, 1024), 256, 0, stream>>>(Xb, wcomb, bcomb, H1b);
  k_trv<<<dim3(1024, 16, 1), 256, 0, stream>>>(H1b, H1t, 1024, HW, 0);

  // --- fc1 + ReLU: pipelined 256x128 GEMM, writes H2b (CHW) + H2t fused ---
  k_mm8<1024, 1, 1><<<1024, 512, 0, stream>>>(
      W1b, 1024, H1t, 1024, b1, H2b, HW, H2t, 512);

  auto cc_block = [&](const ushort* act, ushort* cnn, const ushort* Wqk_,
                      const float* bqk_, const ushort* Wv_, const float* bv_,
                      const float* gam) {
    k_mm<128, 2, 0, 0, 1, 0><<<dim3(512, 1, 1), 256, 0, stream>>>(
        act, 512, 0, Wqk_, 512, 0, bqk_, nullptr, qkt, 128, 0,
        nullptr, 0, 0, nullptr, 0, 0, nullptr, 512);
    k_mm8<512, 0, 0><<<1024, 512, 0, stream>>>(
        Wv_, 512, act, 512, bv_, Vb, HW, nullptr, 0);
    k_trv<<<dim3(4, 4, 512), 256, 0, stream>>>(Vb, vTb, 256, 256, 65536);
    // dual energies: W path E[h][w][v] (batch h); H path E[w][h][g] (batch w)
    k_mm<128, 0, 0, 0, 1, 4><<<2048, 256, 0, stream>>>(
        qkt, 128, 32768, qkt + 64, 128, 32768, nullptr, nullptr, EbW, 256,
        65536, qkt, 32768, 128, qkt + 64, 32768, 128, EbH, 64);
    // fused dual softmax over h (vectorized)
    k_softmax2v<<<256, 256, 0, stream>>>(EbW, AttW, EbH, AttH);
    // dual maps
    k_mm<128, 0, 0, 0, 1, 5><<<4096, 256, 0, stream>>>(
        Vb, HW, 256, AttW, 256, 65536, nullptr, nullptr, Ob, HW, 256,
        vTb, HW, 256, AttH, 256, 65536, THbb, 256);
    // out = gamma*(O + TH^T) + cnn  (bf16 in-place over cnn)
    k_merge3<<<dim3(4, 4, 512), 256, 0, stream>>>(Ob, THbb, cnn, gam, cnn);
  };

  cc_block(H2t, H2b, Wqkb, bqk, Wvb, bv, gamma);
  k_trv<<<dim3(1024, 8, 1), 256, 0, stream>>>(H2b, H2t, 512, HW, 0);
  cc_block(H2t, H2b, Wqk1b, bqk1, Wv1b, bv1, gamma1);

  // --- final fc + instance softmax ---
  k_logits2<<<128, 256, 0, stream>>>(H2b, Wfc, bfc, L);
  k_smax_reduce<<<1, 256, 0, stream>>>(L, red);
  k_smax_write<<<256, 256, 0, stream>>>(L, red, (float*)d_out);
}

// Round 13
// 1178.251 us; speedup vs baseline: 1.0827x; 1.0827x over previous
//
#include <hip/hip_runtime.h>

#define HW 65536
#define SIDE 256

typedef __attribute__((ext_vector_type(8))) short short8v;
typedef __attribute__((ext_vector_type(4))) float f32x4;
typedef __attribute__((ext_vector_type(8))) ushort ushort8v;

__device__ __forceinline__ ushort f2bf(float f) {
  unsigned int u = __builtin_bit_cast(unsigned int, f);
  u = (u + 0x7fff + ((u >> 16) & 1)) >> 16;
  return (ushort)u;
}
__device__ __forceinline__ float bf2f(unsigned int u) {
  return __builtin_bit_cast(float, (u & 0xffffu) << 16);
}
__device__ __forceinline__ float bflo(unsigned int d) {
  return __builtin_bit_cast(float, d << 16);
}
__device__ __forceinline__ float bfhi(unsigned int d) {
  return __builtin_bit_cast(float, d & 0xffff0000u);
}
__device__ __forceinline__ void gld16(const void* g, void* l) {
  __builtin_amdgcn_global_load_lds(
      (const __attribute__((address_space(1))) void*)g,
      (__attribute__((address_space(3))) void*)l, 16, 0, 0);
}

// ---------------------------------------------------------------------------
// Unified weight prep: all bf16 casts + bias concats + combined conv kernel.
__global__ __launch_bounds__(256) void k_prep(
    const float* __restrict__ W1, const float* __restrict__ Wv,
    const float* __restrict__ Wv1, const float* __restrict__ Wq,
    const float* __restrict__ Wk, const float* __restrict__ Wq1,
    const float* __restrict__ Wk1, const float* __restrict__ bq,
    const float* __restrict__ bk, const float* __restrict__ bq1,
    const float* __restrict__ bk1, const float* __restrict__ w7,
    const float* __restrict__ b7, const float* __restrict__ w5,
    const float* __restrict__ b5, const float* __restrict__ w3,
    const float* __restrict__ b3,
    ushort* __restrict__ W1b, ushort* __restrict__ Wvb,
    ushort* __restrict__ Wv1b, ushort* __restrict__ Wqkb,
    ushort* __restrict__ Wqk1b, float* __restrict__ bqk,
    float* __restrict__ bqk1, float* __restrict__ wc, float* __restrict__ bc) {
  const int i = blockIdx.x * 256 + threadIdx.x;
  if (i < 524288) { W1b[i] = f2bf(W1[i]); return; }
  if (i < 786432) { int j = i - 524288; Wvb[j] = f2bf(Wv[j]); return; }
  if (i < 1048576) { int j = i - 786432; Wv1b[j] = f2bf(Wv1[j]); return; }
  if (i < 1081344) { int j = i - 1048576; Wqkb[j] = f2bf(Wq[j]); return; }
  if (i < 1114112) { int j = i - 1081344; Wqkb[32768 + j] = f2bf(Wk[j]); return; }
  if (i < 1146880) { int j = i - 1114112; Wqk1b[j] = f2bf(Wq1[j]); return; }
  if (i < 1179648) { int j = i - 1146880; Wqk1b[32768 + j] = f2bf(Wk1[j]); return; }
  if (i < 1179904) {
    int j = i - 1179648;
    if (j < 64) bqk[j] = bq[j];
    else if (j < 128) bqk[j] = bk[j - 64];
    else if (j < 192) bqk1[j - 128] = bq1[j - 128];
    else bqk1[j - 128] = bk1[j - 192];
    return;
  }
  if (i < 1180928) {
    const int c = i - 1179904;
    float w[49];
#pragma unroll
    for (int t = 0; t < 49; t++) w[t] = w7[c * 49 + t];
    for (int dy = 0; dy < 5; dy++)
      for (int dx = 0; dx < 5; dx++)
        w[(dy + 1) * 7 + (dx + 1)] += w5[c * 25 + dy * 5 + dx];
    for (int dy = 0; dy < 3; dy++)
      for (int dx = 0; dx < 3; dx++)
        w[(dy + 2) * 7 + (dx + 2)] += w3[c * 9 + dy * 3 + dx];
    w[3 * 7 + 3] += 1.0f;
#pragma unroll
    for (int t = 0; t < 49; t++) wc[c * 49 + t] = w[t];
    bc[c] = b7[c] + b5[c] + b3[c];
  }
}

// ---------------------------------------------------------------------------
// Vectorized transpose h0 [N][1024] fp32 -> X [1024][N] bf16.
__global__ __launch_bounds__(256) void k_transpose_nc_v(
    const float* __restrict__ in, ushort* __restrict__ out) {
  __shared__ ushort t[64][64];
  const int c0 = blockIdx.x << 6, r0 = blockIdx.y << 6;
  const int tid = threadIdx.x;
#pragma unroll
  for (int p = 0; p < 2; p++) {
    const int r = (tid >> 3) + p * 32, c8 = tid & 7;
    const float4 f0 = *(const float4*)&in[(size_t)(r0 + r) * 1024 + c0 + c8 * 8];
    const float4 f1 = *(const float4*)&in[(size_t)(r0 + r) * 1024 + c0 + c8 * 8 + 4];
    ushort8v v;
    v[0] = f2bf(f0.x); v[1] = f2bf(f0.y); v[2] = f2bf(f0.z); v[3] = f2bf(f0.w);
    v[4] = f2bf(f1.x); v[5] = f2bf(f1.y); v[6] = f2bf(f1.z); v[7] = f2bf(f1.w);
    *(ushort8v*)&t[r][(c8 ^ ((r >> 3) & 7)) * 8] = v;
  }
  __syncthreads();
#pragma unroll
  for (int p = 0; p < 2; p++) {
    const int c = (tid >> 3) + p * 32, r8 = tid & 7;
    ushort8v v;
#pragma unroll
    for (int j = 0; j < 8; j++) {
      const int rr = r8 * 8 + j;
      v[j] = t[rr][(((c >> 3) ^ r8) << 3) + (c & 7)];
    }
    *(ushort8v*)&out[(size_t)(c0 + c) * HW + r0 + r8 * 8] = v;
  }
}

// ---------------------------------------------------------------------------
// Generic batched bf16 transpose (vectorized): in [R][C] -> out [C][R].
__global__ __launch_bounds__(256) void k_trv(const ushort* __restrict__ in,
    ushort* __restrict__ out, int R, int C, long long bs) {
  __shared__ ushort t[64][64];
  const size_t base = (size_t)blockIdx.z * bs;
  const int c0 = blockIdx.x << 6, r0 = blockIdx.y << 6;
  const int tid = threadIdx.x;
#pragma unroll
  for (int p = 0; p < 2; p++) {
    const int r = (tid >> 3) + p * 32, c8 = tid & 7;
    const ushort8v v = *(const ushort8v*)&in[base + (size_t)(r0 + r) * C + c0 + c8 * 8];
    *(ushort8v*)&t[r][(c8 ^ ((r >> 3) & 7)) * 8] = v;
  }
  __syncthreads();
#pragma unroll
  for (int p = 0; p < 2; p++) {
    const int c = (tid >> 3) + p * 32, r8 = tid & 7;
    ushort8v v;
#pragma unroll
    for (int j = 0; j < 8; j++) {
      const int rr = r8 * 8 + j;
      v[j] = t[rr][(((c >> 3) ^ r8) << 3) + (c & 7)];
    }
    *(ushort8v*)&out[base + (size_t)(c0 + c) * R + r0 + r8 * 8] = v;
  }
}

// ---------------------------------------------------------------------------
// Depthwise 7x7 conv, CHW, bf16 LDS tile. grid (8 stripes, 1024 ch).
__global__ __launch_bounds__(256) void k_dwconv7(const ushort* __restrict__ X,
    const float* __restrict__ wc, const float* __restrict__ bc,
    ushort* __restrict__ out) {
  __shared__ ushort tile[38][272];
  const int c = blockIdx.y;
  const int y0 = blockIdx.x << 5;
  const int tid = threadIdx.x;
  const ushort* Xc = X + (size_t)c * HW;

  float w[49];
#pragma unroll
  for (int i = 0; i < 49; i++) w[i] = wc[c * 49 + i];
  const float bcv = bc[c];

  if (tid < 76) {
    const int r = tid >> 1;
    ushort8v z = {0, 0, 0, 0, 0, 0, 0, 0};
    *(ushort8v*)&tile[r][(tid & 1) ? 264 : 0] = z;
  }
  for (int i = tid; i < 38 * 32; i += 256) {
    const int r = i >> 5, j8 = i & 31;
    const int y = y0 - 3 + r;
    ushort8v v = {0, 0, 0, 0, 0, 0, 0, 0};
    if (y >= 0 && y < SIDE) v = *(const ushort8v*)&Xc[y * SIDE + j8 * 8];
    *(ushort8v*)&tile[r][8 + j8 * 8] = v;
  }
  __syncthreads();

  const int t0 = tid & 63;
  const int ry = (tid >> 6) << 3;
  float acc[8][4] = {};
#pragma unroll
  for (int r = 0; r < 14; r++) {
    const uint2 ua = *(const uint2*)&tile[ry + r][(t0 << 2) + 4];
    const uint2 ub = *(const uint2*)&tile[ry + r][(t0 << 2) + 8];
    const uint2 uc = *(const uint2*)&tile[ry + r][(t0 << 2) + 12];
    float rv[12];
    rv[0] = bflo(ua.x); rv[1] = bfhi(ua.x); rv[2] = bflo(ua.y); rv[3] = bfhi(ua.y);
    rv[4] = bflo(ub.x); rv[5] = bfhi(ub.x); rv[6] = bflo(ub.y); rv[7] = bfhi(ub.y);
    rv[8] = bflo(uc.x); rv[9] = bfhi(uc.x); rv[10] = bflo(uc.y); rv[11] = bfhi(uc.y);
#pragma unroll
    for (int m = 0; m < 8; m++) {
      const int dy = r - m;
      if (dy < 0 || dy > 6) continue;
#pragma unroll
      for (int dx = 0; dx < 7; dx++) {
        const float ww = w[dy * 7 + dx];
#pragma unroll
        for (int o = 0; o < 4; o++) acc[m][o] += ww * rv[o + 1 + dx];
      }
    }
  }
#pragma unroll
  for (int m = 0; m < 8; m++) {
    ushort4 o4 = {f2bf(acc[m][0] + bcv), f2bf(acc[m][1] + bcv),
                  f2bf(acc[m][2] + bcv), f2bf(acc[m][3] + bcv)};
    *(ushort4*)&out[(size_t)c * HW + (y0 + ry + m) * SIDE + (t0 << 2)] = o4;
  }
}

// ---------------------------------------------------------------------------
// 256x128 counted-vmcnt pipelined GEMM for M=512, N=65536 shapes (fc1 / v).
template <int K, int RELU, int TRN>
__global__ __launch_bounds__(512) void k_mm8(
    const ushort* __restrict__ A, int lda,
    const ushort* __restrict__ B, int ldb,
    const float* __restrict__ bias,
    ushort* __restrict__ Cb, int ldc,
    ushort* __restrict__ Ct, int ldt) {
  constexpr int NT = K / 32;
  __shared__ __align__(16) ushort SM[2 * 12288];
  const int tid = threadIdx.x;
  const int lane = tid & 63, wv = tid >> 6;

  const int id = blockIdx.x;
  const int wg = (id & 7) * 128 + (id >> 3);
  const int bm = (wg >> 9) << 8;
  const int bn = (wg & 511) << 7;

  const int l4 = lane >> 2;
  const int sch = (lane & 3) ^ (l4 & 3);
  const int rA0 = (wv * 2) * 16 + l4;
  const int rA1 = (wv * 2 + 1) * 16 + l4;
  const int rB = wv * 16 + l4;
  const ushort* ApS0 = A + (size_t)(bm + rA0) * lda + sch * 8;
  const ushort* ApS1 = A + (size_t)(bm + rA1) * lda + sch * 8;
  const ushort* BpS = B + (size_t)(bn + rB) * ldb + sch * 8;
  const int dA0 = (wv * 2) * 512 + lane * 8;
  const int dA1 = (wv * 2 + 1) * 512 + lane * 8;
  const int dB = wv * 512 + lane * 8;

  const int wm = wv & 3, wn = wv >> 2;
  const int fr = lane & 15, kq = lane >> 4;
  int offA[4], offB[4];
#pragma unroll
  for (int mi = 0; mi < 4; mi++) {
    const int row = wm * 64 + mi * 16 + fr;
    offA[mi] = row * 32 + ((kq ^ (row & 3)) << 3);
  }
#pragma unroll
  for (int ni = 0; ni < 4; ni++) {
    const int row = wn * 64 + ni * 16 + fr;
    offB[ni] = 8192 + row * 32 + ((kq ^ (row & 3)) << 3);
  }

  f32x4 acc[4][4];
#pragma unroll
  for (int mi = 0; mi < 4; mi++)
#pragma unroll
    for (int ni = 0; ni < 4; ni++) acc[mi][ni] = (f32x4){0.f, 0.f, 0.f, 0.f};

#define STAGE8(bufbase, k0)                         \
  do {                                              \
    gld16(ApS0 + (k0), &SM[(bufbase) + dA0]);       \
    gld16(ApS1 + (k0), &SM[(bufbase) + dA1]);       \
    gld16(BpS + (k0), &SM[(bufbase) + 8192 + dB]);  \
  } while (0)

  STAGE8(0, 0);
  STAGE8(12288, 32);
  asm volatile("s_waitcnt vmcnt(3)" ::: "memory");
  __builtin_amdgcn_s_barrier();

  int cur = 0;
#pragma unroll 2
  for (int t = 0; t < NT; ++t) {
    const int base = cur ? 12288 : 0;
    short8v a[4], b2[4];
#pragma unroll
    for (int mi = 0; mi < 4; mi++) a[mi] = *(const short8v*)&SM[base + offA[mi]];
#pragma unroll
    for (int ni = 0; ni < 4; ni++) b2[ni] = *(const short8v*)&SM[base + offB[ni]];
    asm volatile("s_waitcnt lgkmcnt(0)" ::: "memory");
    __builtin_amdgcn_s_barrier();
    const int ts = (t + 2 < NT) ? (t + 2) : (NT - 1);
    STAGE8(base, ts << 5);
    __builtin_amdgcn_s_setprio(1);
#pragma unroll
    for (int mi = 0; mi < 4; mi++)
#pragma unroll
      for (int ni = 0; ni < 4; ni++)
        acc[mi][ni] = __builtin_amdgcn_mfma_f32_16x16x32_bf16(b2[ni], a[mi], acc[mi][ni], 0, 0, 0);
    __builtin_amdgcn_s_setprio(0);
    asm volatile("s_waitcnt vmcnt(3)" ::: "memory");
    __builtin_amdgcn_s_barrier();
    cur ^= 1;
  }
#undef STAGE8
  asm volatile("s_waitcnt vmcnt(0)" ::: "memory");
  __builtin_amdgcn_s_barrier();

  ushort tb[4][4][4];
#pragma unroll
  for (int mi = 0; mi < 4; mi++) {
    const int row = bm + wm * 64 + mi * 16 + fr;
    const float bs1 = bias[row];
#pragma unroll
    for (int ni = 0; ni < 4; ni++) {
      const int col = bn + wn * 64 + ni * 16 + (kq << 2);
      float4 v;
      v.x = acc[mi][ni][0] + bs1; v.y = acc[mi][ni][1] + bs1;
      v.z = acc[mi][ni][2] + bs1; v.w = acc[mi][ni][3] + bs1;
      if (RELU) {
        v.x = fmaxf(v.x, 0.f); v.y = fmaxf(v.y, 0.f);
        v.z = fmaxf(v.z, 0.f); v.w = fmaxf(v.w, 0.f);
      }
      const ushort4 u = {f2bf(v.x), f2bf(v.y), f2bf(v.z), f2bf(v.w)};
      *(ushort4*)&Cb[(size_t)row * ldc + col] = u;
      if (TRN) {
        tb[mi][ni][0] = u.x; tb[mi][ni][1] = u.y;
        tb[mi][ni][2] = u.z; tb[mi][ni][3] = u.w;
      }
    }
  }

  if constexpr (TRN) {
    ushort* St = SM;
#pragma unroll
    for (int hh = 0; hh < 2; hh++) {
      __builtin_amdgcn_s_barrier();
      if (wn == hh) {
#pragma unroll
        for (int mi = 0; mi < 4; mi++) {
          const int cl = wm * 64 + mi * 16 + fr;
#pragma unroll
          for (int ni = 0; ni < 4; ni++) {
            const int nl = ni * 16 + (kq << 2);
#pragma unroll
            for (int r = 0; r < 4; r++) St[(nl + r) * 256 + cl] = tb[mi][ni][r];
          }
        }
      }
      __builtin_amdgcn_s_barrier();
      const int cid = tid * 4;
      const int rowo = cid >> 5;
#pragma unroll
      for (int j = 0; j < 4; j++) {
        const int ch = (cid + j) & 31;
        const ushort8v vv = *(const ushort8v*)&St[rowo * 256 + ch * 8];
        *(ushort8v*)&Ct[(size_t)(bn + hh * 64 + rowo) * ldt + bm + ch * 8] = vv;
      }
    }
  }
}

// ---------------------------------------------------------------------------
// bf16 MFMA GEMM, 128xBN tile, BK=32, 4 waves, global_load_lds staging,
// swapped-operand MFMA (vectorized C stores).
// SWZ: 0 none; 2 grid (2,2,256) flat; 3 grid (4,2,256) flat.
template <int BN, int BIAS, int RELU, int OUTF, int OUTB, int SWZ>
__global__ __launch_bounds__(256) void k_mm(
    const ushort* __restrict__ A, int lda, long long bsA,
    const ushort* __restrict__ B, int ldb, long long bsB,
    const float* __restrict__ bias,
    float* __restrict__ Cf, ushort* __restrict__ Cb, int ldc, long long bsC,
    int K) {
  static_assert(BN == 64 || BN == 128, "BN");
  constexpr int FN = BN / 32;
  __shared__ __align__(16) ushort SMEM[128 * 32 + BN * 32];
  ushort* As = SMEM;
  ushort* Bs = SMEM + 128 * 32;
  const int tid = threadIdx.x;

  int bx, by, bz;
  if constexpr (SWZ == 0) {
    bx = blockIdx.x; by = blockIdx.y; bz = blockIdx.z;
  } else if constexpr (SWZ == 2) {   // logical (2,2,256)
    const int id = blockIdx.x, l = id >> 3;
    bz = (id & 7) * 32 + (l >> 2); bx = l & 1; by = (l >> 1) & 1;
  } else {                            // logical (4,2,256)
    const int id = blockIdx.x, l = id >> 3;
    bz = (id & 7) * 32 + (l >> 3); bx = l & 3; by = (l >> 2) & 1;
  }

  const int bm = bx << 7, bn = by * BN;
  const long long zA = (long long)bz * bsA;
  const long long zB = (long long)bz * bsB;
  const long long zC = (long long)bz * bsC;

  const int sr = tid >> 2, sq = tid & 3;
  const int sw0 = (sr >> 1) & 3;
  const int sw1 = ((sr + 64) >> 1) & 3;
  const ushort* Ap0 = A + zA + (size_t)(bm + sr) * lda + ((sq ^ sw0) << 3);
  const ushort* Ap1 = A + zA + (size_t)(bm + sr + 64) * lda + ((sq ^ sw1) << 3);
  const ushort* Bp0 = B + zB + (size_t)(bn + sr) * ldb + ((sq ^ sw0) << 3);
  const ushort* Bp1 = nullptr;
  if constexpr (BN == 128)
    Bp1 = B + zB + (size_t)(bn + sr + 64) * ldb + ((sq ^ sw1) << 3);
  ushort* wA0 = &As[sr * 32 + sq * 8];
  ushort* wA1 = &As[(sr + 64) * 32 + sq * 8];
  ushort* wB0 = &Bs[sr * 32 + sq * 8];
  ushort* wB1 = nullptr;
  if constexpr (BN == 128) wB1 = &Bs[(sr + 64) * 32 + sq * 8];

  const int lane = tid & 63, wv = tid >> 6;
  const int wm = wv & 1, wn = wv >> 1;
  const int fr = lane & 15, kq = lane >> 4;
  int offA[4], offB[FN];
#pragma unroll
  for (int mi = 0; mi < 4; mi++) {
    const int row = wm * 64 + mi * 16 + fr;
    offA[mi] = row * 32 + ((kq ^ ((row >> 1) & 3)) << 3);
  }
#pragma unroll
  for (int ni = 0; ni < FN; ni++) {
    const int row = wn * (BN / 2) + ni * 16 + fr;
    offB[ni] = row * 32 + ((kq ^ ((row >> 1) & 3)) << 3);
  }

  f32x4 acc[4][FN];
#pragma unroll
  for (int mi = 0; mi < 4; mi++)
#pragma unroll
    for (int ni = 0; ni < FN; ni++) acc[mi][ni] = (f32x4){0.f, 0.f, 0.f, 0.f};

  for (int k0 = 0; k0 < K; k0 += 32) {
    __syncthreads();
    gld16(Ap0 + k0, wA0);
    gld16(Ap1 + k0, wA1);
    gld16(Bp0 + k0, wB0);
    if constexpr (BN == 128) gld16(Bp1 + k0, wB1);
    __syncthreads();
    short8v a[4], b[FN];
#pragma unroll
    for (int mi = 0; mi < 4; mi++) a[mi] = *(const short8v*)&As[offA[mi]];
#pragma unroll
    for (int ni = 0; ni < FN; ni++) b[ni] = *(const short8v*)&Bs[offB[ni]];
#pragma unroll
    for (int mi = 0; mi < 4; mi++)
#pragma unroll
      for (int ni = 0; ni < FN; ni++)
        acc[mi][ni] = __builtin_amdgcn_mfma_f32_16x16x32_bf16(b[ni], a[mi], acc[mi][ni], 0, 0, 0);
  }

#pragma unroll
  for (int mi = 0; mi < 4; mi++) {
    const int row = bm + wm * 64 + mi * 16 + fr;
    const float bs1 = (BIAS == 1) ? bias[row] : 0.f;
#pragma unroll
    for (int ni = 0; ni < FN; ni++) {
      const int col = bn + wn * (BN / 2) + ni * 16 + (kq << 2);
      float4 v;
      v.x = acc[mi][ni][0]; v.y = acc[mi][ni][1];
      v.z = acc[mi][ni][2]; v.w = acc[mi][ni][3];
      if (BIAS == 1) { v.x += bs1; v.y += bs1; v.z += bs1; v.w += bs1; }
      if (BIAS == 2) {
        const float4 bc4 = *(const float4*)&bias[col];
        v.x += bc4.x; v.y += bc4.y; v.z += bc4.z; v.w += bc4.w;
      }
      if (RELU) {
        v.x = fmaxf(v.x, 0.f); v.y = fmaxf(v.y, 0.f);
        v.z = fmaxf(v.z, 0.f); v.w = fmaxf(v.w, 0.f);
      }
      const size_t idx = (size_t)(zC + (size_t)row * ldc + col);
      if (OUTF) *(float4*)&Cf[idx] = v;
      if (OUTB) {
        ushort4 u = {f2bf(v.x), f2bf(v.y), f2bf(v.z), f2bf(v.w)};
        *(ushort4*)&Cb[idx] = u;
      }
    }
  }
}

// ---------------------------------------------------------------------------
// Split-column dual softmax: 4 threads per column (64 h each) + LDS combine.
// Blocks 0..1023: W path (col = flat n = w*256+v, stride HW).
// Blocks 1024..2047: H path (col = w*256+g -> base w*HW+g, stride 256).
__global__ __launch_bounds__(256) void k_softmax4(const ushort* __restrict__ EW,
    ushort* __restrict__ AW, const ushort* __restrict__ EH,
    ushort* __restrict__ AH) {
  __shared__ float sm[4][64], ss[4][64];
  const int b = blockIdx.x, tid = threadIdx.x;
  const int lc = tid & 63, seg = tid >> 6;
  const ushort* E;
  ushort* A;
  size_t base;
  int hs;
  if (b < 1024) {
    E = EW; A = AW; hs = HW;
    base = (size_t)b * 64 + lc;
  } else {
    E = EH; A = AH; hs = 256;
    const int colFlat = (b - 1024) * 64 + lc;
    base = (size_t)(colFlat >> 8) * HW + (colFlat & 255);
  }
  const size_t base_h = base + (size_t)(seg * 64) * hs;
  float m = -3.4e38f, s = 0.f;
  for (int h = 0; h < 64; h++) {
    const float x = bf2f(E[base_h + (size_t)h * hs]);
    const float nm = fmaxf(m, x);
    s = s * __expf(m - nm) + __expf(x - nm);
    m = nm;
  }
  sm[seg][lc] = m;
  ss[seg][lc] = s;
  __syncthreads();
  const float m0 = sm[0][lc], m1 = sm[1][lc], m2 = sm[2][lc], m3 = sm[3][lc];
  const float M = fmaxf(fmaxf(m0, m1), fmaxf(m2, m3));
  const float S = ss[0][lc] * __expf(m0 - M) + ss[1][lc] * __expf(m1 - M) +
                  ss[2][lc] * __expf(m2 - M) + ss[3][lc] * __expf(m3 - M);
  const float inv = 1.0f / S;
  for (int h = 0; h < 64; h++) {
    const size_t i = base_h + (size_t)h * hs;
    A[i] = f2bf(__expf(bf2f(E[i]) - M) * inv);
  }
}

// ---------------------------------------------------------------------------
// Vectorized merge: outB[c][h][w] = f2bf(g*(O + TH^T) + CN). outB aliases CN.
__global__ __launch_bounds__(256) void k_merge3(const ushort* __restrict__ O,
    const ushort* __restrict__ TH, const ushort* __restrict__ CN,
    const float* __restrict__ gammap, ushort* __restrict__ outB) {
  __shared__ ushort t[64][64];
  const float g = *gammap;
  const size_t base = (size_t)blockIdx.z * HW;
  const int h0 = blockIdx.y << 6, w0 = blockIdx.x << 6;
  const int tid = threadIdx.x;
#pragma unroll
  for (int p = 0; p < 2; p++) {
    const int r = (tid >> 3) + p * 32, c8 = tid & 7;
    const ushort8v v = *(const ushort8v*)&TH[base + (w0 + r) * SIDE + h0 + c8 * 8];
    *(ushort8v*)&t[r][(c8 ^ ((r >> 3) & 7)) * 8] = v;
  }
  __syncthreads();
#pragma unroll
  for (int p = 0; p < 2; p++) {
    const int h = (tid >> 3) + p * 32, r8 = tid & 7;
    const size_t idx = base + (h0 + h) * SIDE + w0 + r8 * 8;
    const ushort8v o8 = *(const ushort8v*)&O[idx];
    const ushort8v c8v = *(const ushort8v*)&CN[idx];
    ushort8v res;
#pragma unroll
    for (int j = 0; j < 8; j++) {
      const int rr = r8 * 8 + j;
      const float th = bf2f(t[rr][(((h >> 3) ^ r8) << 3) + (h & 7)]);
      res[j] = f2bf(g * (bf2f(o8[j]) + th) + bf2f(c8v[j]));
    }
    *(ushort8v*)&outB[idx] = res;
  }
}

// ---------------------------------------------------------------------------
// logits, 2 n/thread, uint loads, float2 store.
__global__ __launch_bounds__(256) void k_logits2(const ushort* __restrict__ X,
    const float* __restrict__ Wfc, const float* __restrict__ bfc,
    float* __restrict__ L) {
  const int n0 = (blockIdx.x * 256 + threadIdx.x) * 2;
  float s0 = 0.f, s1 = 0.f;
  for (int j = 0; j < 512; j++) {
    const unsigned int u = *(const unsigned int*)&X[(size_t)j * HW + n0];
    const float wj = Wfc[j];
    s0 += bflo(u) * wj;
    s1 += bfhi(u) * wj;
  }
  float2 o = {s0 + bfc[0], s1 + bfc[0]};
  *(float2*)&L[n0] = o;
}

__global__ __launch_bounds__(256) void k_smax_reduce(const float* __restrict__ L,
                                                     float* __restrict__ red) {
  __shared__ float sm[256];
  const int tid = threadIdx.x;
  float m = -3.4e38f;
  for (int i = tid; i < HW; i += 256) m = fmaxf(m, L[i]);
  sm[tid] = m;
  __syncthreads();
  for (int s = 128; s > 0; s >>= 1) {
    if (tid < s) sm[tid] = fmaxf(sm[tid], sm[tid + s]);
    __syncthreads();
  }
  const float M = sm[0];
  __syncthreads();
  float sum = 0.f;
  for (int i = tid; i < HW; i += 256) sum += expf(L[i] - M);
  sm[tid] = sum;
  __syncthreads();
  for (int s = 128; s > 0; s >>= 1) {
    if (tid < s) sm[tid] += sm[tid + s];
    __syncthreads();
  }
  if (tid == 0) { red[0] = M; red[1] = sm[0]; }
}

__global__ __launch_bounds__(256) void k_smax_write(const float* __restrict__ L,
    const float* __restrict__ red, float* __restrict__ out) {
  const int n = blockIdx.x * 256 + threadIdx.x;
  out[n] = expf(L[n] - red[0]) * (1.0f / red[1]);
}

// ---------------------------------------------------------------------------
extern "C" void kernel_launch(void* const* d_in, const int* in_sizes, int n_in,
                              void* d_out, int out_size, void* d_ws, size_t ws_size,
                              hipStream_t stream) {
  const float* h0 = (const float*)d_in[0];
  const float* w7 = (const float*)d_in[1];
  const float* b7 = (const float*)d_in[2];
  const float* w5 = (const float*)d_in[3];
  const float* b5 = (const float*)d_in[4];
  const float* w3 = (const float*)d_in[5];
  const float* b3 = (const float*)d_in[6];
  const float* W1 = (const float*)d_in[7];
  const float* b1 = (const float*)d_in[8];
  const float* Wq = (const float*)d_in[9];
  const float* bq = (const float*)d_in[10];
  const float* Wk = (const float*)d_in[11];
  const float* bk = (const float*)d_in[12];
  const float* Wv = (const float*)d_in[13];
  const float* bv = (const float*)d_in[14];
  const float* gamma = (const float*)d_in[15];
  const float* Wq1 = (const float*)d_in[16];
  const float* bq1 = (const float*)d_in[17];
  const float* Wk1 = (const float*)d_in[18];
  const float* bk1 = (const float*)d_in[19];
  const float* Wv1 = (const float*)d_in[20];
  const float* bv1 = (const float*)d_in[21];
  const float* gamma1 = (const float*)d_in[22];
  const float* Wfc = (const float*)d_in[23];
  const float* bfc = (const float*)d_in[24];

  char* W = (char*)d_ws;
  const size_t MB = 1 << 20;
  ushort* Xb    = (ushort*)(W + 0);          // [0,128) bf16 CHW conv input
  ushort* H2b   = (ushort*)(W + 0);          // [0,64) bf16 h2/out1/out2 CHW
  ushort* H2t   = (ushort*)(W + 64 * MB);    // [64,128) bf16 act [n][512]
  ushort* qkt   = (ushort*)(W + 128 * MB);   // [128,144) bf16 [n][128]
  ushort* AttW  = (ushort*)(W + 144 * MB);   // [144,176)
  ushort* AttH  = (ushort*)(W + 176 * MB);   // [176,208)
  ushort* H1b   = (ushort*)(W + 256 * MB);   // [256,384) bf16 conv out CHW
  ushort* H1t   = (ushort*)(W + 384 * MB);   // [384,512) bf16 [n][1024]
  ushort* Vb    = (ushort*)(W + 384 * MB);   // [384,448) bf16 (after H1t dead)
  ushort* vTb   = (ushort*)(W + 448 * MB);   // [448,512) bf16
  ushort* Ob    = (ushort*)(W + 512 * MB);   // [512,576) bf16 map-W out
  ushort* THbb  = (ushort*)(W + 576 * MB);   // [576,640) bf16 map-H out
  ushort* EbW   = (ushort*)(W + 640 * MB);   // [640,672) bf16 energy W
  ushort* EbH   = (ushort*)(W + 672 * MB);   // [672,704) bf16 energy H
  ushort* W1b   = (ushort*)(W + 704 * MB);
  ushort* Wvb   = (ushort*)(W + 705 * MB);
  ushort* Wv1b  = (ushort*)(W + 705 * MB + 512 * 1024);
  ushort* Wqkb  = (ushort*)(W + 706 * MB);
  ushort* Wqk1b = (ushort*)(W + 706 * MB + 128 * 1024);
  float*  wcomb = (float*)(W + 706 * MB + 256 * 1024);
  float*  bcomb = (float*)(W + 706 * MB + 464 * 1024);
  float*  bqk   = (float*)(W + 706 * MB + 472 * 1024);
  float*  bqk1  = (float*)(W + 706 * MB + 474 * 1024);
  float*  L     = (float*)(W + 707 * MB);
  float*  red   = (float*)(W + 707 * MB + 256 * 1024);

  // --- unified weight prep (1 launch) ---
  k_prep<<<4613, 256, 0, stream>>>(W1, Wv, Wv1, Wq, Wk, Wq1, Wk1,
                                   bq, bk, bq1, bk1, w7, b7, w5, b5, w3, b3,
                                   W1b, Wvb, Wv1b, Wqkb, Wqk1b, bqk, bqk1,
                                   wcomb, bcomb);

  // --- PPEG ---
  k_transpose_nc_v<<<dim3(16, 1024), 256, 0, stream>>>(h0, Xb);
  k_dwconv7<<<dim3(8, 1024), 256, 0, stream>>>(Xb, wcomb, bcomb, H1b);
  k_trv<<<dim3(1024, 16, 1), 256, 0, stream>>>(H1b, H1t, 1024, HW, 0);

  // --- fc1 + ReLU: pipelined 256x128 GEMM, writes H2b (CHW) + H2t fused ---
  k_mm8<1024, 1, 1><<<1024, 512, 0, stream>>>(
      W1b, 1024, H1t, 1024, b1, H2b, HW, H2t, 512);

  auto cc_block = [&](const ushort* act, ushort* cnn, const ushort* Wqk_,
                      const float* bqk_, const ushort* Wv_, const float* bv_,
                      const float* gam) {
    k_mm<128, 2, 0, 0, 1, 0><<<dim3(512, 1, 1), 256, 0, stream>>>(
        act, 512, 0, Wqk_, 512, 0, bqk_, nullptr, qkt, 128, 0, 512);
    k_mm8<512, 0, 0><<<1024, 512, 0, stream>>>(
        Wv_, 512, act, 512, bv_, Vb, HW, nullptr, 0);
    k_trv<<<dim3(4, 4, 512), 256, 0, stream>>>(Vb, vTb, 256, 256, 65536);
    // energies: W path E[h][w][v] (batch h); H path E[w][h][g] (batch w)
    k_mm<128, 0, 0, 0, 1, 2><<<1024, 256, 0, stream>>>(
        qkt, 128, 32768, qkt + 64, 128, 32768, nullptr, nullptr, EbW, 256,
        65536, 64);
    k_mm<128, 0, 0, 0, 1, 2><<<1024, 256, 0, stream>>>(
        qkt, 32768, 128, qkt + 64, 32768, 128, nullptr, nullptr, EbH, 256,
        65536, 64);
    // split-column dual softmax over h
    k_softmax4<<<2048, 256, 0, stream>>>(EbW, AttW, EbH, AttH);
    // maps
    k_mm<128, 0, 0, 0, 1, 3><<<2048, 256, 0, stream>>>(
        Vb, HW, 256, AttW, 256, 65536, nullptr, nullptr, Ob, HW, 256, 256);
    k_mm<128, 0, 0, 0, 1, 3><<<2048, 256, 0, stream>>>(
        vTb, HW, 256, AttH, 256, 65536, nullptr, nullptr, THbb, HW, 256, 256);
    // out = gamma*(O + TH^T) + cnn  (bf16 in-place over cnn)
    k_merge3<<<dim3(4, 4, 512), 256, 0, stream>>>(Ob, THbb, cnn, gam, cnn);
  };

  cc_block(H2t, H2b, Wqkb, bqk, Wvb, bv, gamma);
  k_trv<<<dim3(1024, 8, 1), 256, 0, stream>>>(H2b, H2t, 512, HW, 0);
  cc_block(H2t, H2b, Wqk1b, bqk1, Wv1b, bv1, gamma1);

  // --- final fc + instance softmax ---
  k_logits2<<<128, 256, 0, stream>>>(H2b, Wfc, bfc, L);
  k_smax_reduce<<<1, 256, 0, stream>>>(L, red);
  k_smax_write<<<256, 256, 0, stream>>>(L, red, (float*)d_out);
}